// Round 1
// baseline (1126.795 us; speedup 1.0000x reference)
//
#include <hip/hip_runtime.h>
#include <hip/hip_bf16.h>

// GATv2 x2 + GlobalAttentionPooling for batched graphs.
// N=50000 nodes, E=500000 edges, G=50 graphs (1000 nodes each, edges in-graph).
// Layer1: IN=128 -> H=4 x D=64 (head-max -> 64). Layer2: 64 -> 4 x 128 (head-max -> 128).
// Pool: softmax(gate) per graph, weighted sum -> [50,128].

#define NN 50000
#define EE 500000
#define GG 50
#define NPG 1000
#define HH 4
#define D1 64
#define D2 128

// ---------------- CSR build ----------------

__global__ void count_dst(const int* __restrict__ dst, int* __restrict__ counts) {
  int i = blockIdx.x * 256 + threadIdx.x;
  if (i < EE) atomicAdd(&counts[dst[i]], 1);
}

__global__ void scan_block(const int* __restrict__ in, int* __restrict__ out,
                           int* __restrict__ bsum, int n) {
  __shared__ int tmp[256];
  int t = threadIdx.x;
  int i = blockIdx.x * 256 + t;
  int v = (i < n) ? in[i] : 0;
  tmp[t] = v;
  __syncthreads();
  for (int off = 1; off < 256; off <<= 1) {
    int a = (t >= off) ? tmp[t - off] : 0;
    __syncthreads();
    tmp[t] += a;
    __syncthreads();
  }
  if (i < n) out[i] = tmp[t] - v;            // exclusive scan within block
  if (t == 255) bsum[blockIdx.x] = tmp[t];   // block total
}

__global__ void scan_bsum(int* __restrict__ bsum, int nb) {
  __shared__ int tmp[256];
  int t = threadIdx.x;
  int v = (t < nb) ? bsum[t] : 0;
  tmp[t] = v;
  __syncthreads();
  for (int off = 1; off < 256; off <<= 1) {
    int a = (t >= off) ? tmp[t - off] : 0;
    __syncthreads();
    tmp[t] += a;
    __syncthreads();
  }
  if (t < nb) bsum[t] = tmp[t] - v;          // exclusive over block sums
}

__global__ void scan_add(int* __restrict__ out, const int* __restrict__ bsum, int n) {
  int i = blockIdx.x * 256 + threadIdx.x;
  if (i < n) out[i] += bsum[blockIdx.x];
}

__global__ void scatter_edges(const int* __restrict__ src, const int* __restrict__ dst,
                              const int* __restrict__ rowstart, int* __restrict__ cursor,
                              int* __restrict__ csr_src) {
  int i = blockIdx.x * 256 + threadIdx.x;
  if (i < EE) {
    int d = dst[i];
    int p = atomicAdd(&cursor[d], 1);
    csr_src[rowstart[d] + p] = src[i];
  }
}

// ---------------- fused dual GEMM: fs = x@Wl+bl, fd = x@Wr+br ----------------
// One block computes R rows x M cols for BOTH weight matrices. x row elements
// are block-uniform -> compiler emits s_loads (scalar cache broadcast).

template<int K, int M, int R>
__launch_bounds__(M)
__global__ void gemm2mat(const float* __restrict__ x,
                         const float* __restrict__ Wl, const float* __restrict__ bl,
                         const float* __restrict__ Wr, const float* __restrict__ br,
                         float* __restrict__ fs, float* __restrict__ fd) {
  const int t = threadIdx.x;
  const int v0 = blockIdx.x * R;
  float accl[R], accr[R];
  const float blv = bl[t], brv = br[t];
#pragma unroll
  for (int r = 0; r < R; ++r) { accl[r] = blv; accr[r] = brv; }
#pragma unroll 4
  for (int k = 0; k < K; ++k) {
    const float wl = Wl[k * M + t];
    const float wr = Wr[k * M + t];
#pragma unroll
    for (int r = 0; r < R; ++r) {
      const float xv = x[(size_t)(v0 + r) * K + k];   // uniform -> s_load
      accl[r] = fmaf(xv, wl, accl[r]);
      accr[r] = fmaf(xv, wr, accr[r]);
    }
  }
#pragma unroll
  for (int r = 0; r < R; ++r) {
    fs[(size_t)(v0 + r) * M + t] = accl[r];
    fd[(size_t)(v0 + r) * M + t] = accr[r];
  }
}

// ---------------- GATv2 layer: one wave per dst node, online softmax ----------------
// lane = h*16 + g16; lane covers dims [g16*DPL, g16*DPL+DPL) of head h.
// Per-16-lane-group shuffle reduction for the logit; head-max via xor 16/32.

template<int D>
__launch_bounds__(256)
__global__ void gat_layer(const float4* __restrict__ fs4, const float4* __restrict__ fd4,
                          const float* __restrict__ attn,
                          const int* __restrict__ rowstart, const int* __restrict__ deg,
                          const int* __restrict__ csr_src,
                          float4* __restrict__ out4) {
  constexpr int DPL = D / 16;   // dims per lane
  constexpr int NV  = DPL / 4;  // float4s per lane
  constexpr int D4  = D / 4;    // float4s per head row
  const int lane = threadIdx.x & 63;
  const int wv   = threadIdx.x >> 6;
  const int v    = (blockIdx.x << 2) + wv;
  if (v >= NN) return;
  const int h   = lane >> 4;
  const int g16 = lane & 15;

  float4 at[NV], fdv[NV];
#pragma unroll
  for (int i = 0; i < NV; ++i) {
    at[i]  = reinterpret_cast<const float4*>(attn)[h * D4 + g16 * NV + i];
    fdv[i] = fd4[(size_t)(v * 4 + h) * D4 + g16 * NV + i];
  }
  const int start = rowstart[v];
  const int n     = deg[v];

  float m = -__builtin_inff();
  float s = 0.f;
  float4 acc[NV];
#pragma unroll
  for (int i = 0; i < NV; ++i) acc[i] = make_float4(0.f, 0.f, 0.f, 0.f);

  for (int e = 0; e < n; ++e) {
    const int u = csr_src[start + e];
    float4 fsu[NV];
#pragma unroll
    for (int i = 0; i < NV; ++i)
      fsu[i] = fs4[(size_t)(u * 4 + h) * D4 + g16 * NV + i];
    float p = 0.f;
#pragma unroll
    for (int i = 0; i < NV; ++i) {
      float tx = fsu[i].x + fdv[i].x;
      float ty = fsu[i].y + fdv[i].y;
      float tz = fsu[i].z + fdv[i].z;
      float tw = fsu[i].w + fdv[i].w;
      // leaky_relu(t,0.2) == max(t, 0.2t) for slope in (0,1)
      p = fmaf(fmaxf(tx, 0.2f * tx), at[i].x, p);
      p = fmaf(fmaxf(ty, 0.2f * ty), at[i].y, p);
      p = fmaf(fmaxf(tz, 0.2f * tz), at[i].z, p);
      p = fmaf(fmaxf(tw, 0.2f * tw), at[i].w, p);
    }
    p += __shfl_xor(p, 1);
    p += __shfl_xor(p, 2);
    p += __shfl_xor(p, 4);
    p += __shfl_xor(p, 8);
    const float mn = fmaxf(m, p);
    const float f  = __expf(m - mn);   // exp(-inf)=0 handles first edge
    const float w  = __expf(p - mn);
    s = s * f + w;
#pragma unroll
    for (int i = 0; i < NV; ++i) {
      acc[i].x = fmaf(acc[i].x, f, w * fsu[i].x);
      acc[i].y = fmaf(acc[i].y, f, w * fsu[i].y);
      acc[i].z = fmaf(acc[i].z, f, w * fsu[i].z);
      acc[i].w = fmaf(acc[i].w, f, w * fsu[i].w);
    }
    m = mn;
  }
  const float rs = (n > 0) ? (1.0f / s) : 0.f;
#pragma unroll
  for (int i = 0; i < NV; ++i) {
    acc[i].x *= rs; acc[i].y *= rs; acc[i].z *= rs; acc[i].w *= rs;
    // max over heads (lanes differing in bits 4,5)
    acc[i].x = fmaxf(acc[i].x, __shfl_xor(acc[i].x, 16));
    acc[i].y = fmaxf(acc[i].y, __shfl_xor(acc[i].y, 16));
    acc[i].z = fmaxf(acc[i].z, __shfl_xor(acc[i].z, 16));
    acc[i].w = fmaxf(acc[i].w, __shfl_xor(acc[i].w, 16));
    acc[i].x = fmaxf(acc[i].x, __shfl_xor(acc[i].x, 32));
    acc[i].y = fmaxf(acc[i].y, __shfl_xor(acc[i].y, 32));
    acc[i].z = fmaxf(acc[i].z, __shfl_xor(acc[i].z, 32));
    acc[i].w = fmaxf(acc[i].w, __shfl_xor(acc[i].w, 32));
  }
  if (h == 0) {
#pragma unroll
    for (int i = 0; i < NV; ++i)
      out4[(size_t)v * D4 + g16 * NV + i] = acc[i];
  }
}

// ---------------- pooling ----------------

__device__ __forceinline__ unsigned int fkey(float f) {
  unsigned int b = __float_as_uint(f);
  return (b & 0x80000000u) ? ~b : (b | 0x80000000u);
}
__device__ __forceinline__ float funkey(unsigned int k) {
  return (k & 0x80000000u) ? __uint_as_float(k & 0x7fffffffu) : __uint_as_float(~k);
}

// gate[v] = h2[v] . gw + gb ; atomicMax per-graph (ordered-uint trick).
__global__ void gate_kernel(const float* __restrict__ h2, const float* __restrict__ gw,
                            const float* __restrict__ gb,
                            float* __restrict__ gate, unsigned int* __restrict__ gmax) {
  const int lane = threadIdx.x & 63;
  const int wv   = threadIdx.x >> 6;
  const int v    = (blockIdx.x << 2) + wv;
  if (v >= NN) return;
  float p = h2[(size_t)v * 128 + lane] * gw[lane]
          + h2[(size_t)v * 128 + 64 + lane] * gw[64 + lane];
  p += __shfl_xor(p, 1);  p += __shfl_xor(p, 2);  p += __shfl_xor(p, 4);
  p += __shfl_xor(p, 8);  p += __shfl_xor(p, 16); p += __shfl_xor(p, 32);
  if (lane == 0) {
    p += gb[0];
    gate[v] = p;
    atomicMax(&gmax[v / NPG], fkey(p));
  }
}

__global__ void expsum_kernel(const float* __restrict__ gate,
                              const unsigned int* __restrict__ gmax,
                              float* __restrict__ ga, float* __restrict__ gsum) {
  int v = blockIdx.x * 256 + threadIdx.x;
  if (v < NN) {
    int g = v / NPG;
    float a = __expf(gate[v] - funkey(gmax[g]));
    ga[v] = a;
    atomicAdd(&gsum[g], a);
  }
}

#define POOL_CH 8
#define POOL_CHUNK (NPG / POOL_CH)

__global__ void pool_acc(const float* __restrict__ h2, const float* __restrict__ ga,
                         const float* __restrict__ gsum, float* __restrict__ out) {
  const int g = blockIdx.x / POOL_CH;
  const int c = blockIdx.x % POOL_CH;
  const int d = threadIdx.x;
  const int n0 = g * NPG + c * POOL_CHUNK;
  float acc = 0.f;
  for (int i = 0; i < POOL_CHUNK; ++i)
    acc = fmaf(ga[n0 + i], h2[(size_t)(n0 + i) * 128 + d], acc);
  atomicAdd(&out[g * 128 + d], acc * (1.0f / gsum[g]));
}

// ---------------- launch ----------------

extern "C" void kernel_launch(void* const* d_in, const int* in_sizes, int n_in,
                              void* d_out, int out_size, void* d_ws, size_t ws_size,
                              hipStream_t stream) {
  const float* x        = (const float*)d_in[0];
  const int*   edge_src = (const int*)d_in[1];
  const int*   edge_dst = (const int*)d_in[2];
  // d_in[3] = node_graph (graph id = v / 1000 by construction; unused)
  const float* Wl1   = (const float*)d_in[4];
  const float* bl1   = (const float*)d_in[5];
  const float* Wr1   = (const float*)d_in[6];
  const float* br1   = (const float*)d_in[7];
  const float* attn1 = (const float*)d_in[8];
  const float* Wl2   = (const float*)d_in[9];
  const float* bl2   = (const float*)d_in[10];
  const float* Wr2   = (const float*)d_in[11];
  const float* br2   = (const float*)d_in[12];
  const float* attn2 = (const float*)d_in[13];
  const float* gate_w = (const float*)d_in[14];
  const float* gate_b = (const float*)d_in[15];
  float* out = (float*)d_out;

  // workspace layout (floats); fs2 aliases fs1+fd1 (dead after gat_layer<64>)
  float* wsf  = (float*)d_ws;
  float* fs1  = wsf;                       // NN*256
  float* fd1  = fs1 + (size_t)NN * 256;    // NN*256
  float* fs2  = fs1;                       // NN*512 (alias)
  float* fd2  = fd1 + (size_t)NN * 256;    // NN*512
  float* h1   = fd2 + (size_t)NN * 512;    // NN*64
  float* h2   = h1  + (size_t)NN * 64;     // NN*128
  float* gate = h2  + (size_t)NN * 128;    // NN
  float* ga   = gate + NN;                 // NN
  float* gsum = ga + NN;                   // GG
  unsigned int* gmax = (unsigned int*)(gsum + GG);  // GG
  int* counts   = (int*)(gmax + GG);       // NN
  int* rowstart = counts + NN;             // NN
  int* cursor   = rowstart + NN;           // NN
  int* csr_src  = cursor + NN;             // EE
  int* bsum     = csr_src + EE;            // 256

  hipMemsetAsync(counts, 0, NN * sizeof(int), stream);
  hipMemsetAsync(cursor, 0, NN * sizeof(int), stream);
  hipMemsetAsync(gmax,   0, GG * sizeof(unsigned int), stream);
  hipMemsetAsync(gsum,   0, GG * sizeof(float), stream);
  hipMemsetAsync(d_out,  0, (size_t)GG * D2 * sizeof(float), stream);

  const int nbN = (NN + 255) / 256;   // 196
  const int nbE = (EE + 255) / 256;

  count_dst<<<nbE, 256, 0, stream>>>(edge_dst, counts);
  scan_block<<<nbN, 256, 0, stream>>>(counts, rowstart, bsum, NN);
  scan_bsum<<<1, 256, 0, stream>>>(bsum, nbN);
  scan_add<<<nbN, 256, 0, stream>>>(rowstart, bsum, NN);
  scatter_edges<<<nbE, 256, 0, stream>>>(edge_src, edge_dst, rowstart, cursor, csr_src);

  gemm2mat<128, 256, 8><<<NN / 8, 256, 0, stream>>>(x, Wl1, bl1, Wr1, br1, fs1, fd1);
  gat_layer<64><<<NN / 4, 256, 0, stream>>>((const float4*)fs1, (const float4*)fd1, attn1,
                                            rowstart, counts, csr_src, (float4*)h1);
  gemm2mat<64, 512, 8><<<NN / 8, 512, 0, stream>>>(h1, Wl2, bl2, Wr2, br2, fs2, fd2);
  gat_layer<128><<<NN / 4, 256, 0, stream>>>((const float4*)fs2, (const float4*)fd2, attn2,
                                             rowstart, counts, csr_src, (float4*)h2);

  gate_kernel<<<NN / 4, 256, 0, stream>>>(h2, gate_w, gate_b, gate, gmax);
  expsum_kernel<<<nbN, 256, 0, stream>>>(gate, gmax, ga, gsum);
  pool_acc<<<GG * POOL_CH, 128, 0, stream>>>(h2, ga, gsum, out);
}

// Round 2
// 569.976 us; speedup vs baseline: 1.9769x; 1.9769x over previous
//
#include <hip/hip_runtime.h>
#include <hip/hip_bf16.h>

// GATv2 x2 + GlobalAttentionPooling for batched graphs.
// N=50000 nodes, E=500000 edges, G=50 graphs (1000 nodes each, edges in-graph).
// Layer1: IN=128 -> H=4 x D=64 (head-max -> 64). Layer2: 64 -> 4 x 128 (head-max -> 128).
// Pool: softmax(gate) per graph, weighted sum -> [50,128].
//
// R1: pooling was 2 kernels doing 50k atomics onto 50 addresses (gate_kernel
// alone 330us at VALUBusy 1.4% -- pure atomic serialization). Replaced with
// one block per graph, all reductions in LDS, zero global atomics.

#define NN 50000
#define EE 500000
#define GG 50
#define NPG 1000
#define HH 4
#define D1 64
#define D2 128

// ---------------- CSR build ----------------

__global__ void count_dst(const int* __restrict__ dst, int* __restrict__ counts) {
  int i = blockIdx.x * 256 + threadIdx.x;
  if (i < EE) atomicAdd(&counts[dst[i]], 1);
}

__global__ void scan_block(const int* __restrict__ in, int* __restrict__ out,
                           int* __restrict__ bsum, int n) {
  __shared__ int tmp[256];
  int t = threadIdx.x;
  int i = blockIdx.x * 256 + t;
  int v = (i < n) ? in[i] : 0;
  tmp[t] = v;
  __syncthreads();
  for (int off = 1; off < 256; off <<= 1) {
    int a = (t >= off) ? tmp[t - off] : 0;
    __syncthreads();
    tmp[t] += a;
    __syncthreads();
  }
  if (i < n) out[i] = tmp[t] - v;            // exclusive scan within block
  if (t == 255) bsum[blockIdx.x] = tmp[t];   // block total
}

__global__ void scan_bsum(int* __restrict__ bsum, int nb) {
  __shared__ int tmp[256];
  int t = threadIdx.x;
  int v = (t < nb) ? bsum[t] : 0;
  tmp[t] = v;
  __syncthreads();
  for (int off = 1; off < 256; off <<= 1) {
    int a = (t >= off) ? tmp[t - off] : 0;
    __syncthreads();
    tmp[t] += a;
    __syncthreads();
  }
  if (t < nb) bsum[t] = tmp[t] - v;          // exclusive over block sums
}

__global__ void scan_add(int* __restrict__ out, const int* __restrict__ bsum, int n) {
  int i = blockIdx.x * 256 + threadIdx.x;
  if (i < n) out[i] += bsum[blockIdx.x];
}

__global__ void scatter_edges(const int* __restrict__ src, const int* __restrict__ dst,
                              const int* __restrict__ rowstart, int* __restrict__ cursor,
                              int* __restrict__ csr_src) {
  int i = blockIdx.x * 256 + threadIdx.x;
  if (i < EE) {
    int d = dst[i];
    int p = atomicAdd(&cursor[d], 1);
    csr_src[rowstart[d] + p] = src[i];
  }
}

// ---------------- fused dual GEMM: fs = x@Wl+bl, fd = x@Wr+br ----------------

template<int K, int M, int R>
__launch_bounds__(M)
__global__ void gemm2mat(const float* __restrict__ x,
                         const float* __restrict__ Wl, const float* __restrict__ bl,
                         const float* __restrict__ Wr, const float* __restrict__ br,
                         float* __restrict__ fs, float* __restrict__ fd) {
  const int t = threadIdx.x;
  const int v0 = blockIdx.x * R;
  float accl[R], accr[R];
  const float blv = bl[t], brv = br[t];
#pragma unroll
  for (int r = 0; r < R; ++r) { accl[r] = blv; accr[r] = brv; }
#pragma unroll 4
  for (int k = 0; k < K; ++k) {
    const float wl = Wl[k * M + t];
    const float wr = Wr[k * M + t];
#pragma unroll
    for (int r = 0; r < R; ++r) {
      const float xv = x[(size_t)(v0 + r) * K + k];   // uniform -> s_load
      accl[r] = fmaf(xv, wl, accl[r]);
      accr[r] = fmaf(xv, wr, accr[r]);
    }
  }
#pragma unroll
  for (int r = 0; r < R; ++r) {
    fs[(size_t)(v0 + r) * M + t] = accl[r];
    fd[(size_t)(v0 + r) * M + t] = accr[r];
  }
}

// ---------------- GATv2 layer: one wave per dst node, online softmax ----------------

template<int D>
__launch_bounds__(256)
__global__ void gat_layer(const float4* __restrict__ fs4, const float4* __restrict__ fd4,
                          const float* __restrict__ attn,
                          const int* __restrict__ rowstart, const int* __restrict__ deg,
                          const int* __restrict__ csr_src,
                          float4* __restrict__ out4) {
  constexpr int DPL = D / 16;   // dims per lane
  constexpr int NV  = DPL / 4;  // float4s per lane
  constexpr int D4  = D / 4;    // float4s per head row
  const int lane = threadIdx.x & 63;
  const int wv   = threadIdx.x >> 6;
  const int v    = (blockIdx.x << 2) + wv;
  if (v >= NN) return;
  const int h   = lane >> 4;
  const int g16 = lane & 15;

  float4 at[NV], fdv[NV];
#pragma unroll
  for (int i = 0; i < NV; ++i) {
    at[i]  = reinterpret_cast<const float4*>(attn)[h * D4 + g16 * NV + i];
    fdv[i] = fd4[(size_t)(v * 4 + h) * D4 + g16 * NV + i];
  }
  const int start = rowstart[v];
  const int n     = deg[v];

  float m = -__builtin_inff();
  float s = 0.f;
  float4 acc[NV];
#pragma unroll
  for (int i = 0; i < NV; ++i) acc[i] = make_float4(0.f, 0.f, 0.f, 0.f);

  for (int e = 0; e < n; ++e) {
    const int u = csr_src[start + e];
    float4 fsu[NV];
#pragma unroll
    for (int i = 0; i < NV; ++i)
      fsu[i] = fs4[(size_t)(u * 4 + h) * D4 + g16 * NV + i];
    float p = 0.f;
#pragma unroll
    for (int i = 0; i < NV; ++i) {
      float tx = fsu[i].x + fdv[i].x;
      float ty = fsu[i].y + fdv[i].y;
      float tz = fsu[i].z + fdv[i].z;
      float tw = fsu[i].w + fdv[i].w;
      p = fmaf(fmaxf(tx, 0.2f * tx), at[i].x, p);
      p = fmaf(fmaxf(ty, 0.2f * ty), at[i].y, p);
      p = fmaf(fmaxf(tz, 0.2f * tz), at[i].z, p);
      p = fmaf(fmaxf(tw, 0.2f * tw), at[i].w, p);
    }
    p += __shfl_xor(p, 1);
    p += __shfl_xor(p, 2);
    p += __shfl_xor(p, 4);
    p += __shfl_xor(p, 8);
    const float mn = fmaxf(m, p);
    const float f  = __expf(m - mn);   // exp(-inf)=0 handles first edge
    const float w  = __expf(p - mn);
    s = s * f + w;
#pragma unroll
    for (int i = 0; i < NV; ++i) {
      acc[i].x = fmaf(acc[i].x, f, w * fsu[i].x);
      acc[i].y = fmaf(acc[i].y, f, w * fsu[i].y);
      acc[i].z = fmaf(acc[i].z, f, w * fsu[i].z);
      acc[i].w = fmaf(acc[i].w, f, w * fsu[i].w);
    }
    m = mn;
  }
  const float rs = (n > 0) ? (1.0f / s) : 0.f;
#pragma unroll
  for (int i = 0; i < NV; ++i) {
    acc[i].x *= rs; acc[i].y *= rs; acc[i].z *= rs; acc[i].w *= rs;
    acc[i].x = fmaxf(acc[i].x, __shfl_xor(acc[i].x, 16));
    acc[i].y = fmaxf(acc[i].y, __shfl_xor(acc[i].y, 16));
    acc[i].z = fmaxf(acc[i].z, __shfl_xor(acc[i].z, 16));
    acc[i].w = fmaxf(acc[i].w, __shfl_xor(acc[i].w, 16));
    acc[i].x = fmaxf(acc[i].x, __shfl_xor(acc[i].x, 32));
    acc[i].y = fmaxf(acc[i].y, __shfl_xor(acc[i].y, 32));
    acc[i].z = fmaxf(acc[i].z, __shfl_xor(acc[i].z, 32));
    acc[i].w = fmaxf(acc[i].w, __shfl_xor(acc[i].w, 32));
  }
  if (h == 0) {
#pragma unroll
    for (int i = 0; i < NV; ++i)
      out4[(size_t)v * D4 + g16 * NV + i] = acc[i];
  }
}

// ---------------- fused pooling: one block per graph, zero global atomics ----------------
// Phase 1: gate[v] = h2[v].gw  (wave-per-node dot, 16 waves cycle 1000 nodes)
// Phase 2: block max  Phase 3: block expsum  Phase 4: alpha in LDS
// Phase 5: weighted sum, 8 node-chunks x 128 dims, LDS partial tree.
// gate_b shifts all logits equally -> cancels in softmax, dropped.

__global__ __launch_bounds__(1024)
void pool_fused(const float* __restrict__ h2, const float* __restrict__ gw,
                float* __restrict__ out) {
  const int g    = blockIdx.x;
  const int t    = threadIdx.x;
  const int lane = t & 63;
  const int w    = t >> 6;        // wave 0..15
  __shared__ float gate_s[NPG];
  __shared__ float red[16];
  __shared__ float fin;
  __shared__ float part[8][128];

  const float gwa = gw[lane], gwb = gw[64 + lane];
  for (int i = w; i < NPG; i += 16) {
    const size_t base = (size_t)(g * NPG + i) * 128;
    float p = h2[base + lane] * gwa + h2[base + 64 + lane] * gwb;
    p += __shfl_xor(p, 1);  p += __shfl_xor(p, 2);  p += __shfl_xor(p, 4);
    p += __shfl_xor(p, 8);  p += __shfl_xor(p, 16); p += __shfl_xor(p, 32);
    if (lane == 0) gate_s[i] = p;
  }
  __syncthreads();

  float m = -__builtin_inff();
  for (int i = t; i < NPG; i += 1024) m = fmaxf(m, gate_s[i]);
  m = fmaxf(m, __shfl_xor(m, 1));  m = fmaxf(m, __shfl_xor(m, 2));
  m = fmaxf(m, __shfl_xor(m, 4));  m = fmaxf(m, __shfl_xor(m, 8));
  m = fmaxf(m, __shfl_xor(m, 16)); m = fmaxf(m, __shfl_xor(m, 32));
  if (lane == 0) red[w] = m;
  __syncthreads();
  if (t == 0) {
    float r = red[0];
#pragma unroll
    for (int j = 1; j < 16; ++j) r = fmaxf(r, red[j]);
    fin = r;
  }
  __syncthreads();
  const float gm = fin;

  float s = 0.f;
  for (int i = t; i < NPG; i += 1024) s += __expf(gate_s[i] - gm);
  s += __shfl_xor(s, 1);  s += __shfl_xor(s, 2);  s += __shfl_xor(s, 4);
  s += __shfl_xor(s, 8);  s += __shfl_xor(s, 16); s += __shfl_xor(s, 32);
  if (lane == 0) red[w] = s;
  __syncthreads();
  if (t == 0) {
    float r = 0.f;
#pragma unroll
    for (int j = 0; j < 16; ++j) r += red[j];
    fin = 1.0f / r;
  }
  __syncthreads();
  const float inv = fin;

  for (int i = t; i < NPG; i += 1024) gate_s[i] = __expf(gate_s[i] - gm) * inv;
  __syncthreads();

  const int d = t & 127;   // dim
  const int c = t >> 7;    // chunk 0..7
  float acc = 0.f;
  for (int i = c; i < NPG; i += 8)
    acc = fmaf(gate_s[i], h2[(size_t)(g * NPG + i) * 128 + d], acc);
  part[c][d] = acc;
  __syncthreads();
  if (c == 0) {
    float r = acc;
#pragma unroll
    for (int j = 1; j < 8; ++j) r += part[j][d];
    out[g * 128 + d] = r;
  }
}

// ---------------- launch ----------------

extern "C" void kernel_launch(void* const* d_in, const int* in_sizes, int n_in,
                              void* d_out, int out_size, void* d_ws, size_t ws_size,
                              hipStream_t stream) {
  const float* x        = (const float*)d_in[0];
  const int*   edge_src = (const int*)d_in[1];
  const int*   edge_dst = (const int*)d_in[2];
  // d_in[3] = node_graph (graph id = v / 1000 by construction; unused)
  const float* Wl1   = (const float*)d_in[4];
  const float* bl1   = (const float*)d_in[5];
  const float* Wr1   = (const float*)d_in[6];
  const float* br1   = (const float*)d_in[7];
  const float* attn1 = (const float*)d_in[8];
  const float* Wl2   = (const float*)d_in[9];
  const float* bl2   = (const float*)d_in[10];
  const float* Wr2   = (const float*)d_in[11];
  const float* br2   = (const float*)d_in[12];
  const float* attn2 = (const float*)d_in[13];
  const float* gate_w = (const float*)d_in[14];
  // d_in[15] = gate_b (cancels in softmax)
  float* out = (float*)d_out;

  // workspace layout (floats); fs2 aliases fs1+fd1 (dead after gat_layer<64>)
  float* wsf  = (float*)d_ws;
  float* fs1  = wsf;                       // NN*256
  float* fd1  = fs1 + (size_t)NN * 256;    // NN*256
  float* fs2  = fs1;                       // NN*512 (alias)
  float* fd2  = fd1 + (size_t)NN * 256;    // NN*512
  float* h1   = fd2 + (size_t)NN * 512;    // NN*64
  float* h2   = h1  + (size_t)NN * 64;     // NN*128
  int* counts   = (int*)(h2 + (size_t)NN * 128);   // NN
  int* rowstart = counts + NN;             // NN
  int* cursor   = rowstart + NN;           // NN
  int* csr_src  = cursor + NN;             // EE
  int* bsum     = csr_src + EE;            // 256

  hipMemsetAsync(counts, 0, NN * sizeof(int), stream);
  hipMemsetAsync(cursor, 0, NN * sizeof(int), stream);

  const int nbN = (NN + 255) / 256;   // 196
  const int nbE = (EE + 255) / 256;

  count_dst<<<nbE, 256, 0, stream>>>(edge_dst, counts);
  scan_block<<<nbN, 256, 0, stream>>>(counts, rowstart, bsum, NN);
  scan_bsum<<<1, 256, 0, stream>>>(bsum, nbN);
  scan_add<<<nbN, 256, 0, stream>>>(rowstart, bsum, NN);
  scatter_edges<<<nbE, 256, 0, stream>>>(edge_src, edge_dst, rowstart, cursor, csr_src);

  gemm2mat<128, 256, 8><<<NN / 8, 256, 0, stream>>>(x, Wl1, bl1, Wr1, br1, fs1, fd1);
  gat_layer<64><<<NN / 4, 256, 0, stream>>>((const float4*)fs1, (const float4*)fd1, attn1,
                                            rowstart, counts, csr_src, (float4*)h1);
  gemm2mat<64, 512, 8><<<NN / 8, 512, 0, stream>>>(h1, Wl2, bl2, Wr2, br2, fs2, fd2);
  gat_layer<128><<<NN / 4, 256, 0, stream>>>((const float4*)fs2, (const float4*)fd2, attn2,
                                             rowstart, counts, csr_src, (float4*)h2);

  pool_fused<<<GG, 1024, 0, stream>>>(h2, gate_w, out);
}

// Round 3
// 488.337 us; speedup vs baseline: 2.3074x; 1.1672x over previous
//
#include <hip/hip_runtime.h>
#include <hip/hip_bf16.h>

// GATv2 x2 + GlobalAttentionPooling for batched graphs.
// N=50000 nodes, E=500000 edges, G=50 graphs (1000 nodes each, edges in-graph).
// Layer1: IN=128 -> H=4 x D=64 (head-max -> 64). Layer2: 64 -> 4 x 128 (head-max -> 128).
// Pool: softmax(gate) per graph, weighted sum -> [50,128].
//
// R1: pooling atomics (50k -> 50 addrs) replaced by block-per-graph LDS. 1127->570us.
// R2: gat_layer was 130us @ FETCH 444MB (unique 205MB): fs/fd now stored bf16
//     (halves traffic, fp32 accumulate) + XCD-aware swizzle so each XCD walks a
//     contiguous ~6-graph range and one graph's tile stays L2-resident.

#define NN 50000
#define EE 500000
#define GG 50
#define NPG 1000
#define HH 4
#define D1 64
#define D2 128

typedef unsigned short ushort_t;
typedef unsigned int uint_t;

// ---------------- CSR build ----------------

__global__ void count_dst(const int* __restrict__ dst, int* __restrict__ counts) {
  int i = blockIdx.x * 256 + threadIdx.x;
  if (i < EE) atomicAdd(&counts[dst[i]], 1);
}

__global__ void scan_block(const int* __restrict__ in, int* __restrict__ out,
                           int* __restrict__ bsum, int n) {
  __shared__ int tmp[256];
  int t = threadIdx.x;
  int i = blockIdx.x * 256 + t;
  int v = (i < n) ? in[i] : 0;
  tmp[t] = v;
  __syncthreads();
  for (int off = 1; off < 256; off <<= 1) {
    int a = (t >= off) ? tmp[t - off] : 0;
    __syncthreads();
    tmp[t] += a;
    __syncthreads();
  }
  if (i < n) out[i] = tmp[t] - v;            // exclusive scan within block
  if (t == 255) bsum[blockIdx.x] = tmp[t];   // block total
}

__global__ void scan_bsum(int* __restrict__ bsum, int nb) {
  __shared__ int tmp[256];
  int t = threadIdx.x;
  int v = (t < nb) ? bsum[t] : 0;
  tmp[t] = v;
  __syncthreads();
  for (int off = 1; off < 256; off <<= 1) {
    int a = (t >= off) ? tmp[t - off] : 0;
    __syncthreads();
    tmp[t] += a;
    __syncthreads();
  }
  if (t < nb) bsum[t] = tmp[t] - v;
}

__global__ void scan_add(int* __restrict__ out, const int* __restrict__ bsum, int n) {
  int i = blockIdx.x * 256 + threadIdx.x;
  if (i < n) out[i] += bsum[blockIdx.x];
}

__global__ void scatter_edges(const int* __restrict__ src, const int* __restrict__ dst,
                              const int* __restrict__ rowstart, int* __restrict__ cursor,
                              int* __restrict__ csr_src) {
  int i = blockIdx.x * 256 + threadIdx.x;
  if (i < EE) {
    int d = dst[i];
    int p = atomicAdd(&cursor[d], 1);
    csr_src[rowstart[d] + p] = src[i];
  }
}

// ---------------- fused dual GEMM: fs = bf16(x@Wl+bl), fd = bf16(x@Wr+br) ----------------

template<int K, int M, int R>
__launch_bounds__(M)
__global__ void gemm2mat(const float* __restrict__ x,
                         const float* __restrict__ Wl, const float* __restrict__ bl,
                         const float* __restrict__ Wr, const float* __restrict__ br,
                         __hip_bfloat16* __restrict__ fs, __hip_bfloat16* __restrict__ fd) {
  const int t = threadIdx.x;
  const int v0 = blockIdx.x * R;
  float accl[R], accr[R];
  const float blv = bl[t], brv = br[t];
#pragma unroll
  for (int r = 0; r < R; ++r) { accl[r] = blv; accr[r] = brv; }
#pragma unroll 4
  for (int k = 0; k < K; ++k) {
    const float wl = Wl[k * M + t];
    const float wr = Wr[k * M + t];
#pragma unroll
    for (int r = 0; r < R; ++r) {
      const float xv = x[(size_t)(v0 + r) * K + k];   // uniform -> s_load
      accl[r] = fmaf(xv, wl, accl[r]);
      accr[r] = fmaf(xv, wr, accr[r]);
    }
  }
#pragma unroll
  for (int r = 0; r < R; ++r) {
    fs[(size_t)(v0 + r) * M + t] = __float2bfloat16(accl[r]);
    fd[(size_t)(v0 + r) * M + t] = __float2bfloat16(accr[r]);
  }
}

// ---------------- GATv2 layer ----------------
// One wave per dst node, online softmax. lane = h*16 + g16; lane covers dims
// [g16*DPL, g16*DPL+DPL) of head h. fs/fd are bf16; unpack to fp32 in-register.
// XCD swizzle: blockIdx&7 selects XCD (dispatch heuristic b%8); each XCD gets a
// contiguous slot range -> sequential graphs -> graph tile stays in its L2.

__device__ __forceinline__ void unpack2(uint_t u, float& lo, float& hi) {
  lo = __uint_as_float(u << 16);
  hi = __uint_as_float(u & 0xffff0000u);
}

template<int N32> struct UV;
template<> struct UV<2> { typedef uint2 T; };
template<> struct UV<4> { typedef uint4 T; };

#define GAT_SLOTS ((NN / 4 + 7) / 8)        // 1563 slots per XCD
#define GAT_GRID  (GAT_SLOTS * 8)           // 12504 blocks

template<int D>
__launch_bounds__(256)
__global__ void gat_layer(const ushort_t* __restrict__ fsb, const ushort_t* __restrict__ fdb,
                          const float* __restrict__ attn,
                          const int* __restrict__ rowstart, const int* __restrict__ deg,
                          const int* __restrict__ csr_src,
                          float4* __restrict__ out4) {
  constexpr int DPL = D / 16;   // dims per lane (8 or 4)
  constexpr int N32 = DPL / 2;  // packed uints per lane (4 or 2)
  constexpr int NV4 = DPL / 4;  // float4s per lane for output (2 or 1)
  constexpr int D4  = D / 4;
  typedef typename UV<N32>::T LT;

  const int b    = blockIdx.x;
  const int slot = (b & 7) * GAT_SLOTS + (b >> 3);
  if (slot >= NN / 4) return;
  const int lane = threadIdx.x & 63;
  const int wv   = threadIdx.x >> 6;
  const int v    = (slot << 2) + wv;
  const int h    = lane >> 4;
  const int g16  = lane & 15;

  float at[DPL], fdv[DPL];
  {
    const float4* attn4 = reinterpret_cast<const float4*>(attn);
#pragma unroll
    for (int i = 0; i < NV4; ++i) {
      float4 a = attn4[h * D4 + g16 * NV4 + i];
      at[4 * i] = a.x; at[4 * i + 1] = a.y; at[4 * i + 2] = a.z; at[4 * i + 3] = a.w;
    }
    LT raw = *reinterpret_cast<const LT*>(fdb + (size_t)(v * 4 + h) * D + g16 * DPL);
    const uint_t* rw = reinterpret_cast<const uint_t*>(&raw);
#pragma unroll
    for (int j = 0; j < N32; ++j) unpack2(rw[j], fdv[2 * j], fdv[2 * j + 1]);
  }
  const int start = rowstart[v];
  const int n     = deg[v];

  float m = -__builtin_inff();
  float s = 0.f;
  float acc[DPL];
#pragma unroll
  for (int i = 0; i < DPL; ++i) acc[i] = 0.f;

  for (int e = 0; e < n; ++e) {
    const int u = csr_src[start + e];
    float fsu[DPL];
    {
      LT raw = *reinterpret_cast<const LT*>(fsb + (size_t)(u * 4 + h) * D + g16 * DPL);
      const uint_t* rw = reinterpret_cast<const uint_t*>(&raw);
#pragma unroll
      for (int j = 0; j < N32; ++j) unpack2(rw[j], fsu[2 * j], fsu[2 * j + 1]);
    }
    float p = 0.f;
#pragma unroll
    for (int i = 0; i < DPL; ++i) {
      float t = fsu[i] + fdv[i];
      p = fmaf(fmaxf(t, 0.2f * t), at[i], p);   // leaky_relu(t,0.2)=max(t,0.2t)
    }
    p += __shfl_xor(p, 1);
    p += __shfl_xor(p, 2);
    p += __shfl_xor(p, 4);
    p += __shfl_xor(p, 8);
    const float mn = fmaxf(m, p);
    const float f  = __expf(m - mn);   // exp(-inf)=0 handles first edge
    const float w  = __expf(p - mn);
    s = s * f + w;
#pragma unroll
    for (int i = 0; i < DPL; ++i) acc[i] = fmaf(acc[i], f, w * fsu[i]);
    m = mn;
  }
  const float rs = (n > 0) ? (1.0f / s) : 0.f;
#pragma unroll
  for (int i = 0; i < DPL; ++i) {
    acc[i] *= rs;
    acc[i] = fmaxf(acc[i], __shfl_xor(acc[i], 16));   // max over heads
    acc[i] = fmaxf(acc[i], __shfl_xor(acc[i], 32));
  }
  if (h == 0) {
#pragma unroll
    for (int i = 0; i < NV4; ++i)
      out4[(size_t)v * D4 + g16 * NV4 + i] =
          make_float4(acc[4 * i], acc[4 * i + 1], acc[4 * i + 2], acc[4 * i + 3]);
  }
}

// ---------------- fused pooling: one block per graph, zero global atomics ----------------

__global__ __launch_bounds__(1024)
void pool_fused(const float* __restrict__ h2, const float* __restrict__ gw,
                float* __restrict__ out) {
  const int g    = blockIdx.x;
  const int t    = threadIdx.x;
  const int lane = t & 63;
  const int w    = t >> 6;        // wave 0..15
  __shared__ float gate_s[NPG];
  __shared__ float red[16];
  __shared__ float fin;
  __shared__ float part[8][128];

  const float gwa = gw[lane], gwb = gw[64 + lane];
  for (int i = w; i < NPG; i += 16) {
    const size_t base = (size_t)(g * NPG + i) * 128;
    float p = h2[base + lane] * gwa + h2[base + 64 + lane] * gwb;
    p += __shfl_xor(p, 1);  p += __shfl_xor(p, 2);  p += __shfl_xor(p, 4);
    p += __shfl_xor(p, 8);  p += __shfl_xor(p, 16); p += __shfl_xor(p, 32);
    if (lane == 0) gate_s[i] = p;
  }
  __syncthreads();

  float m = -__builtin_inff();
  for (int i = t; i < NPG; i += 1024) m = fmaxf(m, gate_s[i]);
  m = fmaxf(m, __shfl_xor(m, 1));  m = fmaxf(m, __shfl_xor(m, 2));
  m = fmaxf(m, __shfl_xor(m, 4));  m = fmaxf(m, __shfl_xor(m, 8));
  m = fmaxf(m, __shfl_xor(m, 16)); m = fmaxf(m, __shfl_xor(m, 32));
  if (lane == 0) red[w] = m;
  __syncthreads();
  if (t == 0) {
    float r = red[0];
#pragma unroll
    for (int j = 1; j < 16; ++j) r = fmaxf(r, red[j]);
    fin = r;
  }
  __syncthreads();
  const float gm = fin;

  float s = 0.f;
  for (int i = t; i < NPG; i += 1024) s += __expf(gate_s[i] - gm);
  s += __shfl_xor(s, 1);  s += __shfl_xor(s, 2);  s += __shfl_xor(s, 4);
  s += __shfl_xor(s, 8);  s += __shfl_xor(s, 16); s += __shfl_xor(s, 32);
  if (lane == 0) red[w] = s;
  __syncthreads();
  if (t == 0) {
    float r = 0.f;
#pragma unroll
    for (int j = 0; j < 16; ++j) r += red[j];
    fin = 1.0f / r;
  }
  __syncthreads();
  const float inv = fin;

  for (int i = t; i < NPG; i += 1024) gate_s[i] = __expf(gate_s[i] - gm) * inv;
  __syncthreads();

  const int d = t & 127;   // dim
  const int c = t >> 7;    // chunk 0..7
  float acc = 0.f;
  for (int i = c; i < NPG; i += 8)
    acc = fmaf(gate_s[i], h2[(size_t)(g * NPG + i) * 128 + d], acc);
  part[c][d] = acc;
  __syncthreads();
  if (c == 0) {
    float r = acc;
#pragma unroll
    for (int j = 1; j < 8; ++j) r += part[j][d];
    out[g * 128 + d] = r;
  }
}

// ---------------- launch ----------------

extern "C" void kernel_launch(void* const* d_in, const int* in_sizes, int n_in,
                              void* d_out, int out_size, void* d_ws, size_t ws_size,
                              hipStream_t stream) {
  const float* x        = (const float*)d_in[0];
  const int*   edge_src = (const int*)d_in[1];
  const int*   edge_dst = (const int*)d_in[2];
  // d_in[3] = node_graph (graph id = v / 1000 by construction; unused)
  const float* Wl1   = (const float*)d_in[4];
  const float* bl1   = (const float*)d_in[5];
  const float* Wr1   = (const float*)d_in[6];
  const float* br1   = (const float*)d_in[7];
  const float* attn1 = (const float*)d_in[8];
  const float* Wl2   = (const float*)d_in[9];
  const float* bl2   = (const float*)d_in[10];
  const float* Wr2   = (const float*)d_in[11];
  const float* br2   = (const float*)d_in[12];
  const float* attn2 = (const float*)d_in[13];
  const float* gate_w = (const float*)d_in[14];
  // d_in[15] = gate_b (cancels in softmax)
  float* out = (float*)d_out;

  // workspace layout; fs2 aliases fs1+fd1 (dead after gat_layer<64>)
  __hip_bfloat16* fs1 = (__hip_bfloat16*)d_ws;            // NN*256 bf16
  __hip_bfloat16* fd1 = fs1 + (size_t)NN * 256;           // NN*256 bf16
  __hip_bfloat16* fs2 = fs1;                              // NN*512 bf16 (alias fs1+fd1)
  __hip_bfloat16* fd2 = fd1 + (size_t)NN * 256;           // NN*512 bf16
  float* h1   = (float*)(fd2 + (size_t)NN * 512);         // NN*64 f32
  float* h2   = h1 + (size_t)NN * 64;                     // NN*128 f32
  int* counts   = (int*)(h2 + (size_t)NN * 128);          // NN
  int* rowstart = counts + NN;
  int* cursor   = rowstart + NN;
  int* csr_src  = cursor + NN;                            // EE
  int* bsum     = csr_src + EE;                           // 256

  hipMemsetAsync(counts, 0, NN * sizeof(int), stream);
  hipMemsetAsync(cursor, 0, NN * sizeof(int), stream);

  const int nbN = (NN + 255) / 256;   // 196
  const int nbE = (EE + 255) / 256;

  count_dst<<<nbE, 256, 0, stream>>>(edge_dst, counts);
  scan_block<<<nbN, 256, 0, stream>>>(counts, rowstart, bsum, NN);
  scan_bsum<<<1, 256, 0, stream>>>(bsum, nbN);
  scan_add<<<nbN, 256, 0, stream>>>(rowstart, bsum, NN);
  scatter_edges<<<nbE, 256, 0, stream>>>(edge_src, edge_dst, rowstart, cursor, csr_src);

  gemm2mat<128, 256, 8><<<NN / 8, 256, 0, stream>>>(x, Wl1, bl1, Wr1, br1, fs1, fd1);
  gat_layer<64><<<GAT_GRID, 256, 0, stream>>>((const ushort_t*)fs1, (const ushort_t*)fd1,
                                              attn1, rowstart, counts, csr_src, (float4*)h1);
  gemm2mat<64, 512, 8><<<NN / 8, 512, 0, stream>>>(h1, Wl2, bl2, Wr2, br2, fs2, fd2);
  gat_layer<128><<<GAT_GRID, 256, 0, stream>>>((const ushort_t*)fs2, (const ushort_t*)fd2,
                                               attn2, rowstart, counts, csr_src, (float4*)h2);

  pool_fused<<<GG, 1024, 0, stream>>>(h2, gate_w, out);
}

// Round 4
// 421.825 us; speedup vs baseline: 2.6712x; 1.1577x over previous
//
#include <hip/hip_runtime.h>
#include <hip/hip_bf16.h>

// GATv2 x2 + GlobalAttentionPooling for batched graphs.
// N=50000 nodes, E=500000 edges, G=50 graphs (1000 nodes each, edges in-graph).
// Layer1: IN=128 -> H=4 x D=64 (head-max -> 64). Layer2: 64 -> 4 x 128 (head-max -> 128).
// Pool: softmax(gate) per graph, weighted sum -> [50,128].
//
// R1: pooling atomics (50k -> 50 addrs) -> block-per-graph LDS. 1127->570us.
// R2: gat_layer bf16 storage + XCD-contiguous swizzle (L2 residency). 570->488us.
// R3: gemm2mat (2x ~98us, fp32 VALU at 66/157 TF) -> bf16 MFMA GEMM
//     (16x16x32, fp32 acc). 128x128 tile, BK=64, LDS pad +8 (2-way bank alias
//     = free). Weights pre-packed B-operand-major; h1 emitted bf16 by gat<64>.

#define NN 50000
#define EE 500000
#define GG 50
#define NPG 1000
#define HH 4

typedef unsigned short ushort_t;
typedef unsigned int uint_t;
typedef __attribute__((ext_vector_type(8))) short bf16x8;
typedef __attribute__((ext_vector_type(4))) float f32x4;

__device__ __forceinline__ ushort_t bf16r(float f) {
  __hip_bfloat16 h = __float2bfloat16(f);
  return *reinterpret_cast<ushort_t*>(&h);
}

// ---------------- CSR build ----------------

__global__ void count_dst(const int* __restrict__ dst, int* __restrict__ counts) {
  int i = blockIdx.x * 256 + threadIdx.x;
  if (i < EE) atomicAdd(&counts[dst[i]], 1);
}

__global__ void scan_block(const int* __restrict__ in, int* __restrict__ out,
                           int* __restrict__ bsum, int n) {
  __shared__ int tmp[256];
  int t = threadIdx.x;
  int i = blockIdx.x * 256 + t;
  int v = (i < n) ? in[i] : 0;
  tmp[t] = v;
  __syncthreads();
  for (int off = 1; off < 256; off <<= 1) {
    int a = (t >= off) ? tmp[t - off] : 0;
    __syncthreads();
    tmp[t] += a;
    __syncthreads();
  }
  if (i < n) out[i] = tmp[t] - v;
  if (t == 255) bsum[blockIdx.x] = tmp[t];
}

__global__ void scan_bsum(int* __restrict__ bsum, int nb) {
  __shared__ int tmp[256];
  int t = threadIdx.x;
  int v = (t < nb) ? bsum[t] : 0;
  tmp[t] = v;
  __syncthreads();
  for (int off = 1; off < 256; off <<= 1) {
    int a = (t >= off) ? tmp[t - off] : 0;
    __syncthreads();
    tmp[t] += a;
    __syncthreads();
  }
  if (t < nb) bsum[t] = tmp[t] - v;
}

__global__ void scan_add(int* __restrict__ out, const int* __restrict__ bsum, int n) {
  int i = blockIdx.x * 256 + threadIdx.x;
  if (i < n) out[i] += bsum[blockIdx.x];
}

__global__ void scatter_edges(const int* __restrict__ src, const int* __restrict__ dst,
                              const int* __restrict__ rowstart, int* __restrict__ cursor,
                              int* __restrict__ csr_src) {
  int i = blockIdx.x * 256 + threadIdx.x;
  if (i < EE) {
    int d = dst[i];
    int p = atomicAdd(&cursor[d], 1);
    csr_src[rowstart[d] + p] = src[i];
  }
}

// ---------------- weight prep: BW[n][k] = bf16(W[k][n]), Wl|Wr concat ----------------

template<int KDIM, int NHALF>
__global__ void prep_w(const float* __restrict__ Wl, const float* __restrict__ Wr,
                       ushort_t* __restrict__ BW) {
  int i = blockIdx.x * 256 + threadIdx.x;   // over (2*NHALF)*KDIM
  int n = i / KDIM, k = i % KDIM;
  const float* W = (n < NHALF) ? Wl : Wr;
  int nn = (n < NHALF) ? n : n - NHALF;
  BW[i] = bf16r(W[(size_t)k * NHALF + nn]);
}

// ---------------- bf16 MFMA GEMM: C[m][n] = A[m][:] . BW[n][:] + bias ----------------
// 128x128 tile, 4 waves x (2 M-bands x 8 N-tiles) of 16x16x32 mfma, fp32 acc.
// LDS rows padded to 72 bf16 (144 B): frag-read start bank = 4*(l16+quad) ->
// exact 2-way aliasing (free, m136); 16B-aligned for b128.

template<int KDIM, bool AF32>
__global__ __launch_bounds__(256)
void gemm_mfma(const float* __restrict__ Af, const ushort_t* __restrict__ Ab,
               const ushort_t* __restrict__ BW,
               const float* __restrict__ bl, const float* __restrict__ br, int nhalf,
               ushort_t* __restrict__ C, int nstride) {
  constexpr int RS = 72;   // LDS row stride (bf16 units)
  __shared__ __align__(16) ushort_t As[128 * RS];
  __shared__ __align__(16) ushort_t Bs[128 * RS];
  const int t = threadIdx.x;
  const int m0 = blockIdx.x * 128, n0 = blockIdx.y * 128;
  const int lane = t & 63, wv = t >> 6;
  const int l16 = lane & 15, quad = lane >> 4;

  f32x4 acc[2][8];
#pragma unroll
  for (int b = 0; b < 2; ++b)
#pragma unroll
    for (int n = 0; n < 8; ++n) acc[b][n] = (f32x4){0.f, 0.f, 0.f, 0.f};

  for (int k0 = 0; k0 < KDIM; k0 += 64) {
    __syncthreads();
    if (AF32) {
      // 64 fp32 per row = 16 float4; t -> (r=t>>4, c4=t&15), 8 passes
      const int r = t >> 4, c4 = t & 15;
#pragma unroll
      for (int p = 0; p < 8; ++p) {
        int m = m0 + r + p * 16;
        int ms = (m < NN) ? m : NN - 1;
        float4 v = *(const float4*)(Af + (size_t)ms * KDIM + k0 + c4 * 4);
        ushort_t* dst = As + (r + p * 16) * RS + c4 * 4;
        dst[0] = bf16r(v.x); dst[1] = bf16r(v.y); dst[2] = bf16r(v.z); dst[3] = bf16r(v.w);
      }
    } else {
      // 64 bf16 per row = 8x16B; t -> (r=t>>3, seg=t&7), 4 passes
      const int r = t >> 3, seg = t & 7;
#pragma unroll
      for (int p = 0; p < 4; ++p) {
        int m = m0 + r + p * 32;
        int ms = (m < NN) ? m : NN - 1;
        *(uint4*)(As + (r + p * 32) * RS + seg * 8) =
            *(const uint4*)(Ab + (size_t)ms * KDIM + k0 + seg * 8);
      }
    }
    {
      const int r = t >> 3, seg = t & 7;
#pragma unroll
      for (int p = 0; p < 4; ++p) {
        *(uint4*)(Bs + (r + p * 32) * RS + seg * 8) =
            *(const uint4*)(BW + (size_t)(n0 + r + p * 32) * KDIM + k0 + seg * 8);
      }
    }
    __syncthreads();
#pragma unroll
    for (int kk = 0; kk < 2; ++kk) {
      bf16x8 a[2];
#pragma unroll
      for (int b = 0; b < 2; ++b)
        a[b] = *(const bf16x8*)(As + (wv * 32 + b * 16 + l16) * RS + kk * 32 + quad * 8);
#pragma unroll
      for (int n = 0; n < 8; ++n) {
        bf16x8 bb = *(const bf16x8*)(Bs + (n * 16 + l16) * RS + kk * 32 + quad * 8);
        acc[0][n] = __builtin_amdgcn_mfma_f32_16x16x32_bf16(a[0], bb, acc[0][n], 0, 0, 0);
        acc[1][n] = __builtin_amdgcn_mfma_f32_16x16x32_bf16(a[1], bb, acc[1][n], 0, 0, 0);
      }
    }
  }
  // epilogue: D[row=quad*4+r][col=l16] per tile; bias from bl|br (block-uniform half)
  const float* bp = (n0 < nhalf) ? bl : br;
  const int nb = (n0 < nhalf) ? n0 : n0 - nhalf;
#pragma unroll
  for (int n = 0; n < 8; ++n) {
    const int col = n0 + n * 16 + l16;
    const float bv = bp[nb + n * 16 + l16];
#pragma unroll
    for (int b = 0; b < 2; ++b) {
      const int rowb = m0 + wv * 32 + b * 16 + quad * 4;
#pragma unroll
      for (int r = 0; r < 4; ++r) {
        if (rowb + r < NN)
          C[(size_t)(rowb + r) * nstride + col] = bf16r(acc[b][n][r] + bv);
      }
    }
  }
}

// ---------------- GATv2 layer ----------------
// One wave per dst node, online softmax. lane = h*16 + g16. fs/fd bf16 slices of
// a combined [node][STRIDE] buffer. XCD swizzle: contiguous slot range per XCD.

__device__ __forceinline__ void unpack2(uint_t u, float& lo, float& hi) {
  lo = __uint_as_float(u << 16);
  hi = __uint_as_float(u & 0xffff0000u);
}

template<int N32> struct UV;
template<> struct UV<2> { typedef uint2 T; };
template<> struct UV<4> { typedef uint4 T; };

#define GAT_SLOTS ((NN / 4 + 7) / 8)        // 1563 slots per XCD
#define GAT_GRID  (GAT_SLOTS * 8)           // 12504 blocks

template<int D, int STRIDE, bool OUTBF>
__global__ __launch_bounds__(256)
void gat_layer(const ushort_t* __restrict__ fsb, const ushort_t* __restrict__ fdb,
               const float* __restrict__ attn,
               const int* __restrict__ rowstart, const int* __restrict__ deg,
               const int* __restrict__ csr_src,
               float4* __restrict__ out4, ushort_t* __restrict__ outb) {
  constexpr int DPL = D / 16;
  constexpr int N32 = DPL / 2;
  constexpr int NV4 = DPL / 4;
  constexpr int D4  = D / 4;
  typedef typename UV<N32>::T LT;

  const int b    = blockIdx.x;
  const int slot = (b & 7) * GAT_SLOTS + (b >> 3);
  if (slot >= NN / 4) return;
  const int lane = threadIdx.x & 63;
  const int wv   = threadIdx.x >> 6;
  const int v    = (slot << 2) + wv;
  const int h    = lane >> 4;
  const int g16  = lane & 15;

  float at[DPL], fdv[DPL];
  {
    const float4* attn4 = reinterpret_cast<const float4*>(attn);
#pragma unroll
    for (int i = 0; i < NV4; ++i) {
      float4 a = attn4[h * D4 + g16 * NV4 + i];
      at[4 * i] = a.x; at[4 * i + 1] = a.y; at[4 * i + 2] = a.z; at[4 * i + 3] = a.w;
    }
    LT raw = *reinterpret_cast<const LT*>(fdb + (size_t)v * STRIDE + h * D + g16 * DPL);
    const uint_t* rw = reinterpret_cast<const uint_t*>(&raw);
#pragma unroll
    for (int j = 0; j < N32; ++j) unpack2(rw[j], fdv[2 * j], fdv[2 * j + 1]);
  }
  const int start = rowstart[v];
  const int n     = deg[v];

  float m = -__builtin_inff();
  float s = 0.f;
  float acc[DPL];
#pragma unroll
  for (int i = 0; i < DPL; ++i) acc[i] = 0.f;

  for (int e = 0; e < n; ++e) {
    const int u = csr_src[start + e];
    float fsu[DPL];
    {
      LT raw = *reinterpret_cast<const LT*>(fsb + (size_t)u * STRIDE + h * D + g16 * DPL);
      const uint_t* rw = reinterpret_cast<const uint_t*>(&raw);
#pragma unroll
      for (int j = 0; j < N32; ++j) unpack2(rw[j], fsu[2 * j], fsu[2 * j + 1]);
    }
    float p = 0.f;
#pragma unroll
    for (int i = 0; i < DPL; ++i) {
      float tt = fsu[i] + fdv[i];
      p = fmaf(fmaxf(tt, 0.2f * tt), at[i], p);
    }
    p += __shfl_xor(p, 1);
    p += __shfl_xor(p, 2);
    p += __shfl_xor(p, 4);
    p += __shfl_xor(p, 8);
    const float mn = fmaxf(m, p);
    const float f  = __expf(m - mn);
    const float w  = __expf(p - mn);
    s = s * f + w;
#pragma unroll
    for (int i = 0; i < DPL; ++i) acc[i] = fmaf(acc[i], f, w * fsu[i]);
    m = mn;
  }
  const float rs = (n > 0) ? (1.0f / s) : 0.f;
#pragma unroll
  for (int i = 0; i < DPL; ++i) {
    acc[i] *= rs;
    acc[i] = fmaxf(acc[i], __shfl_xor(acc[i], 16));
    acc[i] = fmaxf(acc[i], __shfl_xor(acc[i], 32));
  }
  if (h == 0) {
    if constexpr (OUTBF) {
      ushort4 o;
      o.x = bf16r(acc[0]); o.y = bf16r(acc[1]); o.z = bf16r(acc[2]); o.w = bf16r(acc[3]);
      *reinterpret_cast<ushort4*>(outb + (size_t)v * D + g16 * 4) = o;
    } else {
#pragma unroll
      for (int i = 0; i < NV4; ++i)
        out4[(size_t)v * D4 + g16 * NV4 + i] =
            make_float4(acc[4 * i], acc[4 * i + 1], acc[4 * i + 2], acc[4 * i + 3]);
    }
  }
}

// ---------------- fused pooling: one block per graph, zero global atomics ----------------

__global__ __launch_bounds__(1024)
void pool_fused(const float* __restrict__ h2, const float* __restrict__ gw,
                float* __restrict__ out) {
  const int g    = blockIdx.x;
  const int t    = threadIdx.x;
  const int lane = t & 63;
  const int w    = t >> 6;
  __shared__ float gate_s[NPG];
  __shared__ float red[16];
  __shared__ float fin;
  __shared__ float part[8][128];

  const float gwa = gw[lane], gwb = gw[64 + lane];
  for (int i = w; i < NPG; i += 16) {
    const size_t base = (size_t)(g * NPG + i) * 128;
    float p = h2[base + lane] * gwa + h2[base + 64 + lane] * gwb;
    p += __shfl_xor(p, 1);  p += __shfl_xor(p, 2);  p += __shfl_xor(p, 4);
    p += __shfl_xor(p, 8);  p += __shfl_xor(p, 16); p += __shfl_xor(p, 32);
    if (lane == 0) gate_s[i] = p;
  }
  __syncthreads();

  float m = -__builtin_inff();
  for (int i = t; i < NPG; i += 1024) m = fmaxf(m, gate_s[i]);
  m = fmaxf(m, __shfl_xor(m, 1));  m = fmaxf(m, __shfl_xor(m, 2));
  m = fmaxf(m, __shfl_xor(m, 4));  m = fmaxf(m, __shfl_xor(m, 8));
  m = fmaxf(m, __shfl_xor(m, 16)); m = fmaxf(m, __shfl_xor(m, 32));
  if (lane == 0) red[w] = m;
  __syncthreads();
  if (t == 0) {
    float r = red[0];
#pragma unroll
    for (int j = 1; j < 16; ++j) r = fmaxf(r, red[j]);
    fin = r;
  }
  __syncthreads();
  const float gm = fin;

  float s = 0.f;
  for (int i = t; i < NPG; i += 1024) s += __expf(gate_s[i] - gm);
  s += __shfl_xor(s, 1);  s += __shfl_xor(s, 2);  s += __shfl_xor(s, 4);
  s += __shfl_xor(s, 8);  s += __shfl_xor(s, 16); s += __shfl_xor(s, 32);
  if (lane == 0) red[w] = s;
  __syncthreads();
  if (t == 0) {
    float r = 0.f;
#pragma unroll
    for (int j = 0; j < 16; ++j) r += red[j];
    fin = 1.0f / r;
  }
  __syncthreads();
  const float inv = fin;

  for (int i = t; i < NPG; i += 1024) gate_s[i] = __expf(gate_s[i] - gm) * inv;
  __syncthreads();

  const int d = t & 127;
  const int c = t >> 7;
  float acc = 0.f;
  for (int i = c; i < NPG; i += 8)
    acc = fmaf(gate_s[i], h2[(size_t)(g * NPG + i) * 128 + d], acc);
  part[c][d] = acc;
  __syncthreads();
  if (c == 0) {
    float r = acc;
#pragma unroll
    for (int j = 1; j < 8; ++j) r += part[j][d];
    out[g * 128 + d] = r;
  }
}

// ---------------- launch ----------------

extern "C" void kernel_launch(void* const* d_in, const int* in_sizes, int n_in,
                              void* d_out, int out_size, void* d_ws, size_t ws_size,
                              hipStream_t stream) {
  const float* x        = (const float*)d_in[0];
  const int*   edge_src = (const int*)d_in[1];
  const int*   edge_dst = (const int*)d_in[2];
  // d_in[3] = node_graph (graph id = v / 1000 by construction; unused)
  const float* Wl1   = (const float*)d_in[4];
  const float* bl1   = (const float*)d_in[5];
  const float* Wr1   = (const float*)d_in[6];
  const float* br1   = (const float*)d_in[7];
  const float* attn1 = (const float*)d_in[8];
  const float* Wl2   = (const float*)d_in[9];
  const float* bl2   = (const float*)d_in[10];
  const float* Wr2   = (const float*)d_in[11];
  const float* br2   = (const float*)d_in[12];
  const float* attn2 = (const float*)d_in[13];
  const float* gate_w = (const float*)d_in[14];
  // d_in[15] = gate_b (cancels in softmax)
  float* out = (float*)d_out;

  // workspace: fsd1 [NN x 512 bf16] and fsd2 [NN x 1024 bf16] share a union
  // (fsd1 dead once gemm2 runs); h1 bf16 survives into gemm2.
  ushort_t* fsd1 = (ushort_t*)d_ws;                       // NN*512 bf16
  ushort_t* fsd2 = fsd1;                                  // NN*1024 bf16 (union)
  ushort_t* h1b  = fsd2 + (size_t)NN * 1024;              // NN*64 bf16
  float* h2      = (float*)(h1b + (size_t)NN * 64);       // NN*128 f32
  ushort_t* BW1  = (ushort_t*)(h2 + (size_t)NN * 128);    // 512*128 bf16
  ushort_t* BW2  = BW1 + 512 * 128;                       // 1024*64 bf16
  int* counts   = (int*)(BW2 + 1024 * 64);                // NN
  int* rowstart = counts + NN;
  int* cursor   = rowstart + NN;
  int* csr_src  = cursor + NN;                            // EE
  int* bsum     = csr_src + EE;                           // 256

  hipMemsetAsync(counts, 0, NN * sizeof(int), stream);
  hipMemsetAsync(cursor, 0, NN * sizeof(int), stream);

  const int nbN = (NN + 255) / 256;   // 196
  const int nbE = (EE + 255) / 256;
  const int MB  = (NN + 127) / 128;   // 391

  prep_w<128, 256><<<(512 * 128) / 256, 256, 0, stream>>>(Wl1, Wr1, BW1);
  prep_w<64, 512><<<(1024 * 64) / 256, 256, 0, stream>>>(Wl2, Wr2, BW2);

  count_dst<<<nbE, 256, 0, stream>>>(edge_dst, counts);
  scan_block<<<nbN, 256, 0, stream>>>(counts, rowstart, bsum, NN);
  scan_bsum<<<1, 256, 0, stream>>>(bsum, nbN);
  scan_add<<<nbN, 256, 0, stream>>>(rowstart, bsum, NN);
  scatter_edges<<<nbE, 256, 0, stream>>>(edge_src, edge_dst, rowstart, cursor, csr_src);

  gemm_mfma<128, true><<<dim3(MB, 4), 256, 0, stream>>>(
      x, nullptr, BW1, bl1, br1, 256, fsd1, 512);
  gat_layer<64, 512, true><<<GAT_GRID, 256, 0, stream>>>(
      fsd1, fsd1 + 256, attn1, rowstart, counts, csr_src, nullptr, h1b);
  gemm_mfma<64, false><<<dim3(MB, 8), 256, 0, stream>>>(
      nullptr, h1b, BW2, bl2, br2, 512, fsd2, 1024);
  gat_layer<128, 1024, false><<<GAT_GRID, 256, 0, stream>>>(
      fsd2, fsd2 + 512, attn2, rowstart, counts, csr_src, (float4*)h2, nullptr);

  pool_fused<<<GG, 1024, 0, stream>>>(h2, gate_w, out);
}